// Round 4
// baseline (5769.915 us; speedup 1.0000x reference)
//
#include <hip/hip_runtime.h>

#define DD 512
#define BB 256
#define SS 128
#define MTOT (BB*SS)
#define GROUPS 8
#define WPG 32            // workgroups per m-group (each owns 16 d-columns)
#define NWG (GROUPS*WPG)  // 256
#define NTHR 256
#define SLOTS (SS+1)

typedef __bf16 bf16;
typedef float f32x4 __attribute__((ext_vector_type(4)));
typedef __bf16 bf16x8 __attribute__((ext_vector_type(8)));

__device__ __forceinline__ float sigm(float z){ return 1.f/(1.f+__expf(-z)); }

__global__ void k_zero(int* c, int n){ for (int i=threadIdx.x; i<n; i+=NTHR) c[i]=0; }

// LDS map (dynamic, 163840 B total):
//   [0, 98304)        weights: 6 mats x [16 d][512 k] bf16, row-swizzled
//   [98304, 131072)   Hs: [32][512] bf16 swizzled
//   [131072, 163840)  Xs: [32][512] bf16 swizzled  (aliased: f32 partial-exchange)
__launch_bounds__(NTHR, 1)
__global__ void k_main(const float* __restrict__ x, const float* __restrict__ h0,
                       const float* __restrict__ Wu, const float* __restrict__ Uu, const float* __restrict__ bu,
                       const float* __restrict__ Wr, const float* __restrict__ Ur, const float* __restrict__ br,
                       const float* __restrict__ Wh, const float* __restrict__ Uh, const float* __restrict__ bh,
                       bf16* __restrict__ hb0, bf16* __restrict__ hb1,
                       int* __restrict__ cnt, float* __restrict__ out, float* __restrict__ hlast){
  extern __shared__ char smem[];
  char*  Wl  = smem;
  char*  HsB = smem + 98304;
  char*  XsB = smem + 131072;
  float* Xch = (float*)(smem + 131072);

  const int tid  = threadIdx.x;
  const int w    = tid>>6, lane = tid&63;
  const int grp  = blockIdx.x >> 5, widx = blockIdx.x & 31;
  const int m0   = grp*32, d0 = widx*16;
  int* const cbase = cnt + grp*SLOTS;

  // ---- prologue: load + transpose + convert weight slices into LDS ----
  {
    const float* srcs[6] = {Uu, Ur, Uh, Wu, Wr, Wh};
    int d = tid&15, kb = tid>>4;
    for (int M=0; M<6; M++){
      const float* S = srcs[M];
      char* row = Wl + (size_t)(M*16 + d)*1024;
      int swz = (d&7)<<4;
      #pragma unroll 4
      for (int i=0; i<32; i++){
        int k = kb + i*16;
        float v = S[(size_t)k*DD + d0 + d];
        *(bf16*)(row + ((k*2) ^ swz)) = (bf16)v;
      }
    }
  }
  // biases for this WG's d-slice
  const int dcol = d0 + (lane&15);
  const float bu_v = bu[dcol], br_v = br[dcol], bh_v = bh[dcol];
  // fp32 h state in registers (waves 0,1 only)
  float hp[4];
  if (w < 2){
    #pragma unroll
    for (int j=0;j<4;j++)
      hp[j] = h0[(size_t)(m0 + w*16 + (lane>>4)*4 + j)*DD + dcol];
  }
  // init bf16 h shadow (this WG's (m,d) slice)
  {
    int e = tid*2, r = e>>4, c = e&15;
    size_t o = (size_t)(m0+r)*DD + d0 + c;
    hb0[o]   = (bf16)h0[o];
    hb0[o+1] = (bf16)h0[o+1];
  }
  // group barrier slot 0 (init complete)
  __threadfence(); __syncthreads();
  if (tid==0){
    atomicAdd(cbase, 1);
    while (__hip_atomic_load(cbase, __ATOMIC_RELAXED, __HIP_MEMORY_SCOPE_AGENT) < WPG)
      __builtin_amdgcn_s_sleep(2);
  }
  __syncthreads(); __threadfence();

  const int mf = w&1, half = w>>1;
  const int arow = mf*16 + (lane&15);
  const int aswz = (arow&7)<<4;
  const int dswz = ((lane&15)&7)<<4;
  char* const abase = (half? XsB : HsB) + (size_t)arow*1024;
  char* const b0 = Wl + (size_t)((half*3+0)*16 + (lane&15))*1024;
  char* const b1 = Wl + (size_t)((half*3+1)*16 + (lane&15))*1024;
  char* const b2 = Wl + (size_t)((half*3+2)*16 + (lane&15))*1024;
  const int coff = lane>>4;

  for (int st=0; st<SS; st++){
    bf16* hcur = (st&1)? hb1 : hb0;
    bf16* hnxt = (st&1)? hb0 : hb1;
    // ---- stage Hs (bf16 h shadow) and Xs (fp32 x -> bf16) ----
    {
      int r = tid>>3, c8 = tid&7;
      int swz = (r&7)<<4;
      const bf16* gh = hcur + (size_t)(m0+r)*DD + c8*64;
      char* lh = HsB + (size_t)r*1024;
      #pragma unroll
      for (int j=0;j<8;j++){
        bf16x8 v = *(const bf16x8*)(gh + j*8);
        *(bf16x8*)(lh + (((c8*8+j)*16) ^ swz)) = v;
      }
      const float* gx = x + ((size_t)(m0+r)*SS + st)*DD + c8*64;
      char* lx = XsB + (size_t)r*1024;
      #pragma unroll
      for (int j=0;j<8;j++){
        float4 a = *(const float4*)(gx + j*8);
        float4 b = *(const float4*)(gx + j*8 + 4);
        bf16x8 v;
        v[0]=(bf16)a.x; v[1]=(bf16)a.y; v[2]=(bf16)a.z; v[3]=(bf16)a.w;
        v[4]=(bf16)b.x; v[5]=(bf16)b.y; v[6]=(bf16)b.z; v[7]=(bf16)b.w;
        *(bf16x8*)(lx + (((c8*8+j)*16) ^ swz)) = v;
      }
    }
    __syncthreads();
    // ---- K-loop: waves 0,1 = h@U (gates u,r,huh); waves 2,3 = x@W (u,r,xwh) ----
    f32x4 acc0{}, acc1{}, acc2{};
    #pragma unroll
    for (int i=0;i<16;i++){
      int ac = (i*4 + coff)*16;
      bf16x8 av  = *(const bf16x8*)(abase + (ac ^ aswz));
      bf16x8 bv0 = *(const bf16x8*)(b0 + (ac ^ dswz));
      bf16x8 bv1 = *(const bf16x8*)(b1 + (ac ^ dswz));
      bf16x8 bv2 = *(const bf16x8*)(b2 + (ac ^ dswz));
      acc0 = __builtin_amdgcn_mfma_f32_16x16x32_bf16(av, bv0, acc0, 0,0,0);
      acc1 = __builtin_amdgcn_mfma_f32_16x16x32_bf16(av, bv1, acc1, 0,0,0);
      acc2 = __builtin_amdgcn_mfma_f32_16x16x32_bf16(av, bv2, acc2, 0,0,0);
    }
    __syncthreads();             // Xs reads done everywhere; safe to alias-write
    if (half){
      float* dst = Xch + (size_t)(mf*64 + lane)*12;
      *(f32x4*)(dst+0) = acc0; *(f32x4*)(dst+4) = acc1; *(f32x4*)(dst+8) = acc2;
    }
    __syncthreads();
    if (!half){
      const float* src = Xch + (size_t)(mf*64 + lane)*12;
      f32x4 p0 = *(const f32x4*)(src+0);
      f32x4 p1 = *(const f32x4*)(src+4);
      f32x4 p2 = *(const f32x4*)(src+8);
      int mbase = m0 + mf*16 + (lane>>4)*4;
      #pragma unroll
      for (int j=0;j<4;j++){
        float u  = sigm(acc0[j] + p0[j] + bu_v);
        float r  = sigm(acc1[j] + p1[j] + br_v);
        float hh = tanhf(p2[j] + bh_v + r*acc2[j]);
        float hn = (1.f-u)*hp[j] + u*hh;
        hp[j] = hn;
        int m = mbase + j;
        out[((size_t)m*SS + st)*DD + dcol] = hn;
        hnxt[(size_t)m*DD + dcol] = (bf16)hn;
        if (st == SS-1) hlast[(size_t)m*DD + dcol] = hn;
      }
    }
    // ---- group barrier (release h writes; acquire peers') ----
    if (st < SS-1){
      __threadfence(); __syncthreads();
      int* cp = cbase + st + 1;
      if (tid==0){
        atomicAdd(cp, 1);
        while (__hip_atomic_load(cp, __ATOMIC_RELAXED, __HIP_MEMORY_SCOPE_AGENT) < WPG)
          __builtin_amdgcn_s_sleep(2);
      }
      __syncthreads(); __threadfence();
    }
  }
}

extern "C" void kernel_launch(void* const* d_in, const int* in_sizes, int n_in,
                              void* d_out, int out_size, void* d_ws, size_t ws_size,
                              hipStream_t stream){
  const float* x   = (const float*)d_in[0];
  // d_in[1] = item (unused: softmax over length-1 axis == 1)
  const float* h0  = (const float*)d_in[2];
  const float* Wu  = (const float*)d_in[3];
  const float* Uu  = (const float*)d_in[4];
  const float* bu  = (const float*)d_in[5];
  const float* Wr  = (const float*)d_in[6];
  const float* Ur  = (const float*)d_in[7];
  const float* br  = (const float*)d_in[8];
  const float* Wh  = (const float*)d_in[9];
  const float* Uh  = (const float*)d_in[10];
  const float* bh  = (const float*)d_in[11];
  // d_in[12] = Wa (unused)
  float* out   = (float*)d_out;
  float* hlast = out + (size_t)MTOT*DD;

  char* ws = (char*)d_ws;
  bf16* hb0 = (bf16*)(ws);             // 256x512 bf16 = 256 KB
  bf16* hb1 = (bf16*)(ws + 0x40000);   // 256 KB
  int*  cnt = (int*)(ws + 0x80000);    // 8*129 ints

  static bool attr_done = false;
  if (!attr_done){
    hipFuncSetAttribute((const void*)k_main,
                        hipFuncAttributeMaxDynamicSharedMemorySize, 163840);
    attr_done = true;
  }

  k_zero<<<dim3(1), dim3(NTHR), 0, stream>>>(cnt, GROUPS*SLOTS);
  k_main<<<dim3(NWG), dim3(NTHR), 163840, stream>>>(
      x, h0, Wu, Uu, bu, Wr, Ur, br, Wh, Uh, bh, hb0, hb1, cnt, out, hlast);
}

// Round 6
// 1092.755 us; speedup vs baseline: 5.2802x; 5.2802x over previous
//
#include <hip/hip_runtime.h>

#define DD 512
#define BB 256
#define SS 128
#define N3 1536
#define CHUNK 16          // timesteps per G-chunk
#define MCH (BB*CHUNK)    // 4096 rows per chunk gemm
#define MTOT (BB*SS)      // 32768

typedef __bf16 bf16;
typedef float f32x4 __attribute__((ext_vector_type(4)));
typedef __bf16 bf16x8 __attribute__((ext_vector_type(8)));

__device__ __forceinline__ float sigm(float z){ return 1.f/(1.f+__expf(-z)); }

// ---- transpose six 512x512 fp32 matrices into bf16: dst[n][k] = src[k][n] ----
__global__ void k_transpose(const float* __restrict__ s0,const float* __restrict__ s1,
                            const float* __restrict__ s2,const float* __restrict__ s3,
                            const float* __restrict__ s4,const float* __restrict__ s5,
                            bf16* __restrict__ wt, bf16* __restrict__ ut){
  __shared__ float tile[32][33];
  int z = blockIdx.z;
  const float* src = z==0?s0:z==1?s1:z==2?s2:z==3?s3:z==4?s4:s5;
  bf16* dst = (z<3)? (wt + (size_t)z*DD*DD) : (ut + (size_t)(z-3)*DD*DD);
  int bx = blockIdx.x*32, by = blockIdx.y*32;
  int tx = threadIdx.x, ty = threadIdx.y;   // 32 x 8
  for (int i=0;i<32;i+=8) tile[ty+i][tx] = src[(size_t)(by+ty+i)*DD + bx+tx];
  __syncthreads();
  for (int i=0;i<32;i+=8) dst[(size_t)(bx+ty+i)*DD + by+tx] = (bf16)tile[tx][ty+i];
}

// ---- init h buffers from fp32 h0 ----
__global__ void k_init(const float* __restrict__ h0, float* __restrict__ hf0, float* __restrict__ hf1,
                       bf16* __restrict__ hb0, bf16* __restrict__ hb1){
  int i = blockIdx.x*256 + threadIdx.x;
  float v = h0[i];
  hf0[i] = v; hf1[i] = v;
  bf16 b = (bf16)v;
  hb0[i] = b; hb1[i] = b;
}

// ---- Gc[mg][n] = bf16(X[xrow(mg)])·Wt[n] + bias[n] (fp32 out); mg=b*CHUNK+tt, n=gate*512+d ----
__global__ __launch_bounds__(256) void k_gemmG(const float* __restrict__ X, const bf16* __restrict__ Wt,
                        const float* __restrict__ bu,const float* __restrict__ br,const float* __restrict__ bh,
                        float* __restrict__ G, int c16){
  __shared__ bf16 As[128][40];
  __shared__ bf16 Bs[128][40];
  int m0 = blockIdx.x*128, n0 = blockIdx.y*128;
  int tid = threadIdx.x;
  int w = tid>>6, lane = tid&63;
  int wm = (w&1)*64, wn = (w>>1)*64;
  int lrow = lane&15, lk = (lane>>4)*8;
  f32x4 acc[4][4] = {};
  for (int k0=0;k0<DD;k0+=32){
    for (int p=0;p<2;p++){
      int i = p*256 + tid;
      int r = i>>2, ch = i&3;
      int mg = m0 + r;                                  // chunk-local row
      int xrow = ((mg>>4)*SS) + c16 + (mg&15);          // global x row (b*S + t)
      const float* px = X + (size_t)xrow*DD + k0 + ch*8;
      float4 a = *reinterpret_cast<const float4*>(px);
      float4 b = *reinterpret_cast<const float4*>(px+4);
      bf16x8 v;
      v[0]=(bf16)a.x; v[1]=(bf16)a.y; v[2]=(bf16)a.z; v[3]=(bf16)a.w;
      v[4]=(bf16)b.x; v[5]=(bf16)b.y; v[6]=(bf16)b.z; v[7]=(bf16)b.w;
      *reinterpret_cast<bf16x8*>(&As[r][ch*8]) = v;
      *reinterpret_cast<bf16x8*>(&Bs[r][ch*8]) =
          *reinterpret_cast<const bf16x8*>(Wt + (size_t)(n0+r)*DD + k0 + ch*8);
    }
    __syncthreads();
    bf16x8 a[4], b[4];
    for (int mr=0;mr<4;mr++) a[mr] = *reinterpret_cast<bf16x8*>(&As[wm+mr*16+lrow][lk]);
    for (int nr=0;nr<4;nr++) b[nr] = *reinterpret_cast<bf16x8*>(&Bs[wn+nr*16+lrow][lk]);
    for (int mr=0;mr<4;mr++)
      for (int nr=0;nr<4;nr++)
        acc[mr][nr] = __builtin_amdgcn_mfma_f32_16x16x32_bf16(a[mr], b[nr], acc[mr][nr], 0,0,0);
    __syncthreads();
  }
  for (int nr=0;nr<4;nr++){
    int n = n0 + wn + nr*16 + (lane&15);
    int g = n>>9; int nn = n & 511;
    float bv = (g==0?bu[nn]:g==1?br[nn]:bh[nn]);
    for (int mr=0;mr<4;mr++){
      for (int j=0;j<4;j++){
        int m = m0 + wm + mr*16 + (lane>>4)*4 + j;
        G[(size_t)m*N3 + n] = acc[mr][nr][j] + bv;
      }
    }
  }
}

// ---- one recurrent step: acc = h_prev @ [Uu|Ur|Uh], then gate update ----
// grid (8,16): 32-row x 32-d tiles; BK=64, double-buffered LDS, load-early/write-late
__global__ __launch_bounds__(256) void k_step(const bf16* __restrict__ Ut, const float* __restrict__ G,
                       const float* __restrict__ hpf, const bf16* __restrict__ hpb,
                       float* __restrict__ hnf, bf16* __restrict__ hnb,
                       float* __restrict__ out, float* __restrict__ hlast, int t){
  __shared__ bf16 Hs[2][32][72];
  __shared__ bf16 Us[2][96][72];
  const int m0 = blockIdx.x*32, d0 = blockIdx.y*32;
  const int tid = threadIdx.x;
  const int w = tid>>6, lane = tid&63;
  const int wm = (w&1)*16, wd = (w>>1)*16;
  const int tt = t & (CHUNK-1);
  // staging coords (per thread): 1 Hs chunk + 3 Us chunks of 16B
  const int hrow = tid>>3, hc8 = tid&7;
  const bf16* hsrc = hpb + (size_t)(m0+hrow)*DD + hc8*8;
  int urow[3], uc8[3];
  const bf16* usrc[3];
  #pragma unroll
  for (int p=0;p<3;p++){
    int i = p*256 + tid;
    urow[p] = i>>3; uc8[p] = i&7;
    int g = urow[p]>>5, dc = urow[p]&31;
    usrc[p] = Ut + (size_t)(g*DD + d0 + dc)*DD + uc8[p]*8;
  }
  // prologue: stage k-tile 0 into buf 0
  *reinterpret_cast<bf16x8*>(&Hs[0][hrow][hc8*8]) = *reinterpret_cast<const bf16x8*>(hsrc);
  #pragma unroll
  for (int p=0;p<3;p++)
    *reinterpret_cast<bf16x8*>(&Us[0][urow[p]][uc8[p]*8]) = *reinterpret_cast<const bf16x8*>(usrc[p]);
  __syncthreads();

  f32x4 acc[3] = {};
  const int lrow = lane&15, lk = (lane>>4)*8;
  #pragma unroll
  for (int it=0; it<8; it++){
    const int cur = it&1, nxt = (it+1)&1;
    bf16x8 rh; bf16x8 ru[3];
    if (it < 7){
      int k0 = (it+1)*64;
      rh = *reinterpret_cast<const bf16x8*>(hsrc + k0);
      #pragma unroll
      for (int p=0;p<3;p++) ru[p] = *reinterpret_cast<const bf16x8*>(usrc[p] + k0);
    }
    bf16x8 a0 = *reinterpret_cast<bf16x8*>(&Hs[cur][wm+lrow][lk]);
    bf16x8 a1 = *reinterpret_cast<bf16x8*>(&Hs[cur][wm+lrow][lk+32]);
    #pragma unroll
    for (int g=0;g<3;g++){
      bf16x8 b0 = *reinterpret_cast<bf16x8*>(&Us[cur][g*32+wd+lrow][lk]);
      bf16x8 b1 = *reinterpret_cast<bf16x8*>(&Us[cur][g*32+wd+lrow][lk+32]);
      acc[g] = __builtin_amdgcn_mfma_f32_16x16x32_bf16(a0, b0, acc[g], 0,0,0);
      acc[g] = __builtin_amdgcn_mfma_f32_16x16x32_bf16(a1, b1, acc[g], 0,0,0);
    }
    if (it < 7){
      *reinterpret_cast<bf16x8*>(&Hs[nxt][hrow][hc8*8]) = rh;
      #pragma unroll
      for (int p=0;p<3;p++)
        *reinterpret_cast<bf16x8*>(&Us[nxt][urow[p]][uc8[p]*8]) = ru[p];
      __syncthreads();
    }
  }
  // epilogue: gate fusion
  const int d = d0 + wd + (lane&15);
  #pragma unroll
  for (int j=0;j<4;j++){
    int m = m0 + wm + (lane>>4)*4 + j;
    size_t grow = ((size_t)m*CHUNK + tt)*N3;
    float gu = G[grow + d];
    float gr = G[grow + 512 + d];
    float gh = G[grow + 1024 + d];
    float u  = sigm(gu + acc[0][j]);
    float r  = sigm(gr + acc[1][j]);
    float hh = tanhf(gh + r*acc[2][j]);
    float hp = hpf[(size_t)m*DD + d];
    float hn = (1.f-u)*hp + u*hh;
    hnf[(size_t)m*DD + d] = hn;
    hnb[(size_t)m*DD + d] = (bf16)hn;
    out[((size_t)m*SS + t)*DD + d] = hn;
    if (t == SS-1) hlast[(size_t)m*DD + d] = hn;
  }
}

extern "C" void kernel_launch(void* const* d_in, const int* in_sizes, int n_in,
                              void* d_out, int out_size, void* d_ws, size_t ws_size,
                              hipStream_t stream){
  const float* x   = (const float*)d_in[0];
  // d_in[1] = item (unused: softmax over length-1 axis == 1)
  const float* h0  = (const float*)d_in[2];
  const float* Wu  = (const float*)d_in[3];
  const float* Uu  = (const float*)d_in[4];
  const float* bu  = (const float*)d_in[5];
  const float* Wr  = (const float*)d_in[6];
  const float* Ur  = (const float*)d_in[7];
  const float* br  = (const float*)d_in[8];
  const float* Wh  = (const float*)d_in[9];
  const float* Uh  = (const float*)d_in[10];
  const float* bh  = (const float*)d_in[11];
  // d_in[12] = Wa (unused)
  float* out   = (float*)d_out;
  float* hlast = out + (size_t)MTOT*DD;

  char* ws = (char*)d_ws;
  bf16*  Wt  = (bf16*)(ws);                 // 1536x512 bf16 = 1.5 MB
  bf16*  Ut  = (bf16*)(ws + 0x180000);      // 1536x512 bf16 = 1.5 MB
  float* Gc  = (float*)(ws + 0x300000);     // 4096x1536 f32 = 24 MB (per-chunk gates)
  float* hf0 = (float*)(ws + 0x1F00000);    // 256x512 f32
  float* hf1 = (float*)(ws + 0x1F80000);
  bf16*  hb0 = (bf16*)(ws + 0x2000000);     // 256x512 bf16
  bf16*  hb1 = (bf16*)(ws + 0x2040000);     // ends at 0x2080000 = 32.5 MB

  k_transpose<<<dim3(16,16,6), dim3(32,8), 0, stream>>>(Wu,Wr,Wh,Uu,Ur,Uh,Wt,Ut);
  k_init<<<dim3(512), dim3(256), 0, stream>>>(h0, hf0, hf1, hb0, hb1);
  for (int c=0;c<SS/CHUNK;c++){
    k_gemmG<<<dim3(MCH/128,12), dim3(256), 0, stream>>>(x, Wt, bu,br,bh, Gc, c*CHUNK);
    for (int tt=0;tt<CHUNK;tt++){
      int t = c*CHUNK + tt;
      float* hpf = (t&1)? hf1: hf0; float* hnf = (t&1)? hf0: hf1;
      bf16*  hpb = (t&1)? hb1: hb0; bf16*  hnb = (t&1)? hb0: hb1;
      k_step<<<dim3(8,16), dim3(256), 0, stream>>>(Ut, Gc, hpf, hpb, hnf, hnb, out, hlast, t);
    }
  }
}